// Round 11
// baseline (254.622 us; speedup 1.0000x reference)
//
#include <hip/hip_runtime.h>
#include <math.h>

// R11: producer/consumer (R10 structure) resized for 2 blocks/CU.
// 448 thr = 7 waves: waves 0..5 FIR (CPW=14, proven codegen, predicated
// boundary reads), wave 6 = scan + stage.
// Per chunk: [A] FIR reads xs -> ybuf[b]  ||  scan wave scans ybuf[b^1]
//            bar
//            [B] scan wave stages chunk c+1 -> xs via global_load_lds
//                (width 16, linear dest = wave-base + lane*16; no data VGPRs)
//            bar
// LDS = xs 20.5K + ybuf dbuf 41.1K + feat = ~62.9 KB -> 2 blocks/CU;
// 14 waves/CU needs only VGPR<=128 (measured 80-108 for this FIR).
// Weights read as conv_w[k] (uniform const index -> s_load, SGPR-resident):
// removes 64 ds_reads per wave-chunk and the wsh LDS buffer.
// Scan wave: 81 channels = 2 interleaved in-lane recurrences (ch=lane,
// ch2=64+lane for lane<17); independent dep-chains pipeline.

#define NTH      448
#define NFIR     384
#define CPW      14
#define TC       64
#define YSTRIDE  65
#define NCHUNK   8         // 7*64 + 52 = 500
#define T_LEN    500
#define C_OUT    81

__global__ __launch_bounds__(NTH)
void snn_ps2_kernel(const float* __restrict__ x,
                    const float* __restrict__ conv_w,
                    const float* __restrict__ conv_b,
                    const float* __restrict__ bn_gamma,
                    const float* __restrict__ bn_beta,
                    const float* __restrict__ bn_mean,
                    const float* __restrict__ bn_var,
                    const float* __restrict__ plif_w,
                    const float* __restrict__ fc_w,
                    const float* __restrict__ fc_b,
                    float* __restrict__ out)
{
    __shared__ float xs[80 * TC];              // 20480 B (single buffer)
    __shared__ float ybuf[2][C_OUT * YSTRIDE]; // 42120 B
    __shared__ float feat[C_OUT];              // total ~62.9 KiB

    const int tid  = threadIdx.x;
    const int n    = blockIdx.x;
    const int lane = tid & 63;
    const float* xn = x + (size_t)n * (80 * T_LEN);

    // ---- prologue: stage chunk 0 (all threads, float4; regs die here) ----
    for (int i = tid; i < 1280; i += NTH) {
        const int cr = i >> 4, t4 = i & 15;
        float4 v4 = *reinterpret_cast<const float4*>(xn + cr * T_LEN + t4 * 4);
        *reinterpret_cast<float4*>(&xs[cr * TC + t4 * 4]) = v4;
    }

    // ---- scan-wave per-lane state (wave 6): two channels per lane ----
    float v1 = 0.0f, c1 = 0.0f, iv1 = 0.0f, bb1 = 0.0f;
    float v2 = 0.0f, c2 = 0.0f, iv2 = 0.0f, bb2 = 0.0f;
    float decay = 0.0f;
    int ch2 = 64;                               // clamped: pointer stays in-range
    if (tid >= NFIR) {
        decay = 1.0f / (1.0f + expf(-plif_w[0]));
        const int ch1 = lane;                   // 0..63, all < 81
        iv1 = bn_gamma[ch1] * rsqrtf(bn_var[ch1] + 1e-5f);
        bb1 = conv_b[0] * iv1 + bn_beta[ch1] - bn_mean[ch1] * iv1;
        ch2 = 64 + (lane < 17 ? lane : 0);      // 64..80
        iv2 = bn_gamma[ch2] * rsqrtf(bn_var[ch2] + 1e-5f);
        bb2 = conv_b[0] * iv2 + bn_beta[ch2] - bn_mean[ch2] * iv2;
    }
    __syncthreads();

    for (int c = 0; c < NCHUNK; ++c) {
        const int b = c & 1;

        if (tid < NFIR) {
            // ================= FIR producers (waves 0..5) =================
            const int co0 = (tid >> 6) * CPW;   // 0,14,28,42,56,70
            float acc[CPW];
            float win[CPW];                     // win[(k+r)%CPW] = row co0+k+r-32
            #pragma unroll
            for (int r = 0; r < CPW; ++r) acc[r] = 0.0f;
            const int row0 = co0 - 32;
            #pragma unroll
            for (int m = 0; m < CPW - 1; ++m) {
                const int row = row0 + m;       // wave-uniform -> scalar branch
                win[m] = ((unsigned)row < 80u) ? xs[row * TC + lane] : 0.0f;
            }
            #pragma unroll
            for (int k = 0; k < 64; ++k) {
                const int row = row0 + k + (CPW - 1);
                win[(k + CPW - 1) % CPW] =
                    ((unsigned)row < 80u) ? xs[row * TC + lane] : 0.0f;
                const float wk = conv_w[k];     // uniform const idx -> s_load
                #pragma unroll
                for (int r = 0; r < CPW; ++r)
                    acc[r] = fmaf(wk, win[(k + r) % CPW], acc[r]);
            }
            #pragma unroll
            for (int r = 0; r < CPW; ++r) {
                const int co = co0 + r;
                if (co < C_OUT) ybuf[b][co * YSTRIDE + lane] = acc[r];
            }
        } else if (c > 0) {
            // ============ scan wave: PLIF for chunk c-1 ============
            const float* yr1 = &ybuf[b ^ 1][lane * YSTRIDE];
            const float* yr2 = &ybuf[b ^ 1][ch2 * YSTRIDE];
            #pragma unroll 4
            for (int t = 0; t < TC; ++t) {
                const float xt1 = fmaf(yr1[t], iv1, bb1);
                v1 = fmaf(xt1 - v1, decay, v1);
                const bool s1 = (v1 >= 1.0f);
                c1 += s1 ? 1.0f : 0.0f;
                v1 = s1 ? 0.0f : v1;
                if (lane < 17) {
                    const float xt2 = fmaf(yr2[t], iv2, bb2);
                    v2 = fmaf(xt2 - v2, decay, v2);
                    const bool s2 = (v2 >= 1.0f);
                    c2 += s2 ? 1.0f : 0.0f;
                    v2 = s2 ? 0.0f : v2;
                }
            }
        }
        __syncthreads();   // [A] ybuf[b] ready; all xs reads complete

        if (tid >= NFIR && c < NCHUNK - 1) {
            // ===== stage chunk c+1 -> xs, async global->LDS, no data regs ====
            const int t0n = (c + 1) * TC;
            #pragma unroll
            for (int j = 0; j < 20; ++j) {
                const int i  = j * 64 + lane;   // 0..1279
                const int cr = i >> 4, t4 = i & 15;
                int toff = t0n + t4 * 4;
                if (toff > 496) toff = 496;     // tail dup; cols 52..63 unused
                __builtin_amdgcn_global_load_lds(
                    (const __attribute__((address_space(1))) void*)(xn + cr * T_LEN + toff),
                    (__attribute__((address_space(3))) void*)(&xs[(size_t)i * 4]),
                    16, 0, 0);
            }
        }
        __syncthreads();   // [B] barrier drain waits scan wave's vmcnt -> xs staged
    }

    // ---- epilogue: scan chunk 7 (52 cols) from ybuf[1] ----
    if (tid >= NFIR) {
        const float* yr1 = &ybuf[1][lane * YSTRIDE];
        const float* yr2 = &ybuf[1][ch2 * YSTRIDE];
        #pragma unroll 4
        for (int t = 0; t < 52; ++t) {
            const float xt1 = fmaf(yr1[t], iv1, bb1);
            v1 = fmaf(xt1 - v1, decay, v1);
            const bool s1 = (v1 >= 1.0f);
            c1 += s1 ? 1.0f : 0.0f;
            v1 = s1 ? 0.0f : v1;
            if (lane < 17) {
                const float xt2 = fmaf(yr2[t], iv2, bb2);
                v2 = fmaf(xt2 - v2, decay, v2);
                const bool s2 = (v2 >= 1.0f);
                c2 += s2 ? 1.0f : 0.0f;
                v2 = s2 ? 0.0f : v2;
            }
        }
        feat[lane] = c1 * (1.0f / 500.0f);
        if (lane < 17) feat[64 + lane] = c2 * (1.0f / 500.0f);
    }
    __syncthreads();

    if (tid < 3) {
        float o = fc_b[tid];
        #pragma unroll 3
        for (int cc = 0; cc < C_OUT; ++cc)
            o = fmaf(feat[cc], fc_w[tid * C_OUT + cc], o);
        out[n * 3 + tid] = o;
    }
}

extern "C" void kernel_launch(void* const* d_in, const int* in_sizes, int n_in,
                              void* d_out, int out_size, void* d_ws, size_t ws_size,
                              hipStream_t stream)
{
    const float* x        = (const float*)d_in[0];
    const float* conv_w   = (const float*)d_in[1];
    const float* conv_b   = (const float*)d_in[2];
    const float* bn_gamma = (const float*)d_in[3];
    const float* bn_beta  = (const float*)d_in[4];
    const float* bn_mean  = (const float*)d_in[5];
    const float* bn_var   = (const float*)d_in[6];
    const float* plif_w   = (const float*)d_in[7];
    const float* fc_w     = (const float*)d_in[8];
    const float* fc_b     = (const float*)d_in[9];
    float* out            = (float*)d_out;

    snn_ps2_kernel<<<1024, NTH, 0, stream>>>(
        x, conv_w, conv_b, bn_gamma, bn_beta, bn_mean, bn_var,
        plif_w, fc_w, fc_b, out);
}

// Round 12
// 236.462 us; speedup vs baseline: 1.0768x; 1.0768x over previous
//
#include <hip/hip_runtime.h>
#include <math.h>

// R12: R10's producer/consumer topology (single barrier/chunk, everything
// overlapped), resized for 2 blocks/CU and spill-free staging.
// 640 thr = 10 waves: waves 0..7 FIR (CPW=11, co0=11w, 88>=81; UNPADDED xs
// + predicated boundary reads = R5/R7/R8-proven codegen), waves 8..9 scan
// (81 lanes, 1 channel each) + stage (global_load_lds width16, async, no
// data registers -> R10's 41MB pf-spill eliminated).
// Per chunk c (ONE barrier):
//   FIR: xs[b] -> ybuf[b]   ||  scan waves: issue stage of chunk c+1 ->
//   xs[b^1] (async), then scan chunk c-1 from ybuf[b^1].
// TC=60 (9 chunks: 8x60+20), YSTRIDE=61 (odd -> conflict-free).
// LDS = 2*80*60*4 + 2*81*61*4 + feat = ~78.3 KB -> 2 blocks/CU = 20 waves
// (needs VGPR<=102; R10 measured 84). Co-resident block hides barrier
// bubbles + scan serial chain.

#define NTH      640
#define NFIR     512
#define CPW      11
#define TC       60
#define YSTRIDE  61
#define NCHUNK   9         // 8*60 + 20 = 500
#define T_LEN    500
#define C_OUT    81
#define NF4      900       // not used; items = 80 rows * 15 f4 = 1200

__global__ __launch_bounds__(NTH)
void snn_ps3_kernel(const float* __restrict__ x,
                    const float* __restrict__ conv_w,
                    const float* __restrict__ conv_b,
                    const float* __restrict__ bn_gamma,
                    const float* __restrict__ bn_beta,
                    const float* __restrict__ bn_mean,
                    const float* __restrict__ bn_var,
                    const float* __restrict__ plif_w,
                    const float* __restrict__ fc_w,
                    const float* __restrict__ fc_b,
                    float* __restrict__ out)
{
    __shared__ float xs[2][80 * TC];           // 2 x 19200 B
    __shared__ float ybuf[2][C_OUT * YSTRIDE]; // 2 x 19764 B
    __shared__ float wsh[64];
    __shared__ float feat[C_OUT];              // total ~78.3 KiB

    const int tid  = threadIdx.x;
    const int n    = blockIdx.x;
    const int lane = tid & 63;
    const float* xn = x + (size_t)n * (80 * T_LEN);

    if (tid < 64) wsh[tid] = conv_w[tid];

    // ---- prologue: stage chunk 0 -> xs[0] (80 rows x 15 float4 = 1200) ----
    for (int i = tid; i < 1200; i += NTH) {
        const int cr = i / 15, t4 = i - cr * 15;
        float4 v4 = *reinterpret_cast<const float4*>(xn + cr * T_LEN + t4 * 4);
        *reinterpret_cast<float4*>(&xs[0][cr * TC + t4 * 4]) = v4;
    }

    // ---- scan-wave per-lane state (waves 8..9: channel = sid, sid<81) ----
    const int sid = tid - NFIR;                // <0 for FIR threads
    float v = 0.0f, cnt = 0.0f, iv = 0.0f, bb = 0.0f, decay = 0.0f;
    if (tid >= NFIR) {
        decay = 1.0f / (1.0f + expf(-plif_w[0]));
        const int ch = (sid < C_OUT) ? sid : 0;
        iv = bn_gamma[ch] * rsqrtf(bn_var[ch] + 1e-5f);
        bb = conv_b[0] * iv + bn_beta[ch] - bn_mean[ch] * iv;
    }
    __syncthreads();

    for (int c = 0; c < NCHUNK; ++c) {
        const int b = c & 1;

        if (tid < NFIR) {
            // ================= FIR producers (waves 0..7) =================
            const int co0 = (tid >> 6) * CPW;  // 0,11,...,77
            const float* xsb = xs[b];
            float acc[CPW];
            float win[CPW];                    // win[(k+r)%CPW] = row co0+k+r-32
            #pragma unroll
            for (int r = 0; r < CPW; ++r) acc[r] = 0.0f;
            const int row0 = co0 - 32;
            #pragma unroll
            for (int m = 0; m < CPW - 1; ++m) {
                const int row = row0 + m;      // wave-uniform -> scalar cmp
                win[m] = ((unsigned)row < 80u) ? xsb[row * TC + lane] : 0.0f;
            }
            #pragma unroll
            for (int k = 0; k < 64; ++k) {
                const int row = row0 + k + (CPW - 1);
                win[(k + CPW - 1) % CPW] =
                    ((unsigned)row < 80u) ? xsb[row * TC + lane] : 0.0f;
                const float wk = wsh[k];       // LDS broadcast
                #pragma unroll
                for (int r = 0; r < CPW; ++r)
                    acc[r] = fmaf(wk, win[(k + r) % CPW], acc[r]);
            }
            const int tcols = (c == NCHUNK - 1) ? 20 : TC;
            if (lane < tcols) {
                #pragma unroll
                for (int r = 0; r < CPW; ++r) {
                    const int co = co0 + r;
                    if (co < C_OUT) ybuf[b][co * YSTRIDE + lane] = acc[r];
                }
            }
        } else {
            // ========== consumers (waves 8..9): stage async, then scan =====
            if (c < NCHUNK - 1) {
                const int t0n = (c + 1) * TC;
                float* xsn = xs[b ^ 1];
                #pragma unroll
                for (int j = 0; j < 10; ++j) {
                    const int i = j * 128 + sid;       // 0..1279
                    if (i < 1200) {
                        const int cr = i / 15, t4 = i - cr * 15;
                        int toff = t0n + t4 * 4;
                        if (toff > 496) toff = 496;    // tail dup; unused cols
                        __builtin_amdgcn_global_load_lds(
                            (const __attribute__((address_space(1))) void*)
                                (xn + cr * T_LEN + toff),
                            (__attribute__((address_space(3))) void*)
                                (&xsn[(size_t)i * 4]),
                            16, 0, 0);
                    }
                }
            }
            if (c > 0 && sid < C_OUT) {
                const float* yrow = &ybuf[b ^ 1][sid * YSTRIDE];
                #pragma unroll 4
                for (int t = 0; t < TC; ++t) {
                    const float xt = fmaf(yrow[t], iv, bb);   // BN
                    v = fmaf(xt - v, decay, v);               // v += (x-v)*decay
                    const bool s = (v >= 1.0f);
                    cnt += s ? 1.0f : 0.0f;
                    v = s ? 0.0f : v;
                }
            }
        }
        __syncthreads();   // drains vmcnt of stagers -> xs[b^1] ready
    }

    // ---- epilogue: scan chunk 8 (20 cols) from ybuf[0] ----
    if (tid >= NFIR && sid < C_OUT) {
        const float* yrow = &ybuf[0][sid * YSTRIDE];
        #pragma unroll 4
        for (int t = 0; t < 20; ++t) {
            const float xt = fmaf(yrow[t], iv, bb);
            v = fmaf(xt - v, decay, v);
            const bool s = (v >= 1.0f);
            cnt += s ? 1.0f : 0.0f;
            v = s ? 0.0f : v;
        }
        feat[sid] = cnt * (1.0f / 500.0f);
    }
    __syncthreads();

    if (tid < 3) {
        float o = fc_b[tid];
        #pragma unroll 3
        for (int cc = 0; cc < C_OUT; ++cc)
            o = fmaf(feat[cc], fc_w[tid * C_OUT + cc], o);
        out[n * 3 + tid] = o;
    }
}

extern "C" void kernel_launch(void* const* d_in, const int* in_sizes, int n_in,
                              void* d_out, int out_size, void* d_ws, size_t ws_size,
                              hipStream_t stream)
{
    const float* x        = (const float*)d_in[0];
    const float* conv_w   = (const float*)d_in[1];
    const float* conv_b   = (const float*)d_in[2];
    const float* bn_gamma = (const float*)d_in[3];
    const float* bn_beta  = (const float*)d_in[4];
    const float* bn_mean  = (const float*)d_in[5];
    const float* bn_var   = (const float*)d_in[6];
    const float* plif_w   = (const float*)d_in[7];
    const float* fc_w     = (const float*)d_in[8];
    const float* fc_b     = (const float*)d_in[9];
    float* out            = (float*)d_out;

    snn_ps3_kernel<<<1024, NTH, 0, stream>>>(
        x, conv_w, conv_b, bn_gamma, bn_beta, bn_mean, bn_var,
        plif_w, fc_w, fc_b, out);
}

// Round 13
// 118.821 us; speedup vs baseline: 2.1429x; 1.9901x over previous
//
#include <hip/hip_runtime.h>
#include <math.h>

// R13 = R10 verbatim, with ONE change: the consumer waves' phase order is
// load -> ds_write -> scan (was load -> scan -> write). R10's pf[10] regs
// were live ACROSS the scan loop -> partial spill (WRITE_SIZE 41 MB on the
// consumer critical path). Writing pf to xs[b^1] immediately kills the regs
// before the scan; the staging latency is covered by the 8 co-resident FIR
// waves (not by the scan), and only the end-of-chunk barrier needs the
// writes done (~1100cy << FIR ~2800cy/SIMD).
// Topology (R10-proven): 640 thr = 10 waves. Waves 0..7: FIR, CPW=11,
// PADDED xs (pure ds_read+fma, no cndmask). Waves 8..9: stage+scan.
// Double-buffered xs and ybuf; ONE barrier per chunk. LDS ~117 KiB.

#define NTH      640
#define NFIR     512       // threads in FIR waves
#define CPW      11
#define TC       64
#define XROWS    151       // max padded row read = co0(77)+73 = 150
#define YSTRIDE  65        // +1 pad: conflict-free column reads in scan
#define NCHUNK   8         // 7*64 + 52 = 500
#define T_LEN    500
#define C_OUT    81

__global__ __launch_bounds__(NTH)
void snn_fused_ps_kernel(const float* __restrict__ x,
                         const float* __restrict__ conv_w,
                         const float* __restrict__ conv_b,
                         const float* __restrict__ bn_gamma,
                         const float* __restrict__ bn_beta,
                         const float* __restrict__ bn_mean,
                         const float* __restrict__ bn_var,
                         const float* __restrict__ plif_w,
                         const float* __restrict__ fc_w,
                         const float* __restrict__ fc_b,
                         float* __restrict__ out)
{
    __shared__ float xs[2][XROWS * TC];        // 2 x 38656 B
    __shared__ float ybuf[2][C_OUT * YSTRIDE]; // 2 x 21060 B
    __shared__ float wsh[64];
    __shared__ float feat[C_OUT];              // total ~117.3 KiB

    const int tid  = threadIdx.x;
    const int n    = blockIdx.x;
    const float* xn = x + (size_t)n * (80 * T_LEN);

    if (tid < 64) wsh[tid] = conv_w[tid];

    // ---- zero the FIR pad rows of BOTH buffers (written once, never again)
    for (int i = tid; i < 32 * TC; i += NTH) { xs[0][i] = 0.0f; xs[1][i] = 0.0f; }
    for (int i = tid; i < (XROWS - 112) * TC; i += NTH) {
        xs[0][112 * TC + i] = 0.0f; xs[1][112 * TC + i] = 0.0f;
    }
    // ---- stage chunk 0 -> xs[0] rows 32..111 (all threads, 2 f4 each)
    for (int i = tid; i < 1280; i += NTH) {
        const int cr = i >> 4, t4 = i & 15;
        float4 v4 = *reinterpret_cast<const float4*>(xn + cr * T_LEN + t4 * 4);
        *reinterpret_cast<float4*>(&xs[0][(cr + 32) * TC + t4 * 4]) = v4;
    }

    // scan-wave per-lane state (threads 512..639; channel = tid-512)
    float v = 0.0f, cnt = 0.0f, inv_c = 0.0f, bb_c = 0.0f, decay = 0.0f;
    if (tid >= NFIR) {
        const int ch = tid - NFIR;
        decay = 1.0f / (1.0f + expf(-plif_w[0]));
        if (ch < C_OUT) {
            inv_c = bn_gamma[ch] * rsqrtf(bn_var[ch] + 1e-5f);
            bb_c  = conv_b[0] * inv_c + bn_beta[ch] - bn_mean[ch] * inv_c;
        }
    }
    __syncthreads();

    for (int c = 0; c < NCHUNK; ++c) {
        const int b = c & 1;

        if (tid < NFIR) {
            // ================= FIR producers =================
            const int lane = tid & 63;
            const int co0  = (tid >> 6) * CPW;
            const float* xsb = xs[b];

            float acc[CPW];
            float win[CPW];                   // win[(k+r)%CPW] = padded row co0+k+r
            #pragma unroll
            for (int r = 0; r < CPW; ++r) acc[r] = 0.0f;
            const int base = co0 * TC + lane;
            #pragma unroll
            for (int m = 0; m < CPW - 1; ++m) win[m] = xsb[base + m * TC];
            #pragma unroll
            for (int k = 0; k < 64; ++k) {
                win[(k + CPW - 1) % CPW] = xsb[base + (k + CPW - 1) * TC];
                const float wk = wsh[k];      // LDS broadcast
                #pragma unroll
                for (int r = 0; r < CPW; ++r)
                    acc[r] = fmaf(wk, win[(k + r) % CPW], acc[r]);
            }
            #pragma unroll
            for (int r = 0; r < CPW; ++r) {
                const int co = co0 + r;
                if (co < C_OUT) ybuf[b][co * YSTRIDE + lane] = acc[r];
            }
        } else {
            // ============ stage-then-scan consumers ============
            const int sid = tid - NFIR;       // 0..127

            // 1) load AND write next chunk -> xs[b^1]; pf regs die HERE
            //    (R10 held them across the scan -> 41MB scratch spill).
            //    Latency is covered by the co-resident FIR waves, not by us.
            if (c < NCHUNK - 1) {
                const int t0n = (c + 1) * TC;
                float4 pf[10];
                #pragma unroll
                for (int s = 0; s < 10; ++s) {
                    const int i  = s * 128 + sid;   // 1280 items
                    const int cr = i >> 4, t4 = i & 15;
                    int toff = t0n + t4 * 4;
                    if (toff > 496) toff = 496;     // tail dup; cols 52..63 unused
                    pf[s] = *reinterpret_cast<const float4*>(xn + cr * T_LEN + toff);
                }
                #pragma unroll
                for (int s = 0; s < 10; ++s) {
                    const int i  = s * 128 + sid;
                    const int cr = i >> 4, t4 = i & 15;
                    *reinterpret_cast<float4*>(&xs[b ^ 1][(cr + 32) * TC + t4 * 4]) = pf[s];
                }
            }

            // 2) PLIF scan of chunk c-1 (64 cols; chunk 7 done in epilogue)
            if (c > 0 && sid < C_OUT) {
                const float* yrow = &ybuf[b ^ 1][sid * YSTRIDE];
                #pragma unroll 4
                for (int t = 0; t < TC; ++t) {
                    const float xt = fmaf(yrow[t], inv_c, bb_c);   // BN
                    v = fmaf(xt - v, decay, v);                    // v += (x-v)*decay
                    const bool s = (v >= 1.0f);
                    cnt += s ? 1.0f : 0.0f;
                    v = s ? 0.0f : v;
                }
            }
        }
        __syncthreads();   // single barrier per chunk
    }

    // epilogue: scan chunk 7 (52 cols) from ybuf[1]
    if (tid >= NFIR) {
        const int sid = tid - NFIR;
        if (sid < C_OUT) {
            const float* yrow = &ybuf[1][sid * YSTRIDE];
            #pragma unroll 4
            for (int t = 0; t < 52; ++t) {
                const float xt = fmaf(yrow[t], inv_c, bb_c);
                v = fmaf(xt - v, decay, v);
                const bool s = (v >= 1.0f);
                cnt += s ? 1.0f : 0.0f;
                v = s ? 0.0f : v;
            }
            feat[sid] = cnt * (1.0f / 500.0f);
        }
    }
    __syncthreads();

    if (tid < 3) {
        float o = fc_b[tid];
        #pragma unroll 3
        for (int cc = 0; cc < C_OUT; ++cc)
            o = fmaf(feat[cc], fc_w[tid * C_OUT + cc], o);
        out[n * 3 + tid] = o;
    }
}

extern "C" void kernel_launch(void* const* d_in, const int* in_sizes, int n_in,
                              void* d_out, int out_size, void* d_ws, size_t ws_size,
                              hipStream_t stream)
{
    const float* x        = (const float*)d_in[0];
    const float* conv_w   = (const float*)d_in[1];
    const float* conv_b   = (const float*)d_in[2];
    const float* bn_gamma = (const float*)d_in[3];
    const float* bn_beta  = (const float*)d_in[4];
    const float* bn_mean  = (const float*)d_in[5];
    const float* bn_var   = (const float*)d_in[6];
    const float* plif_w   = (const float*)d_in[7];
    const float* fc_w     = (const float*)d_in[8];
    const float* fc_b     = (const float*)d_in[9];
    float* out            = (float*)d_out;

    snn_fused_ps_kernel<<<1024, NTH, 0, stream>>>(
        x, conv_w, conv_b, bn_gamma, bn_beta, bn_mean, bn_var,
        plif_w, fc_w, fc_b, out);
}